// Round 4
// baseline (2163.665 us; speedup 1.0000x reference)
//
#include <hip/hip_runtime.h>

typedef __attribute__((ext_vector_type(8))) short bfrag;   // 8 bf16 (4 VGPRs)
typedef __attribute__((ext_vector_type(4))) float f32x4;   // MFMA C/D
typedef __attribute__((ext_vector_type(4))) int i32x4;     // 16B moves

#define NT 512      // seq len
#define NB 64       // batch
#define KD 512      // D == H == 512
#define NG 2048     // 4*H gate rows
#define GB 4        // batch blocks (16 batch each)
#define GH 16       // h-slices (32 dims each)

#define YS_SZ (NT * NB * KD)          // 16777216
#define HT_OFF YS_SZ
#define CT_OFF (YS_SZ + NB * KD)

#define MB_BLK_ELEMS 8192             // 16 batch x 512 dims bf16 per block
#define MB_PAR_ELEMS (GB * MB_BLK_ELEMS)

__device__ __forceinline__ unsigned short f2bf(float f) {
  unsigned u = __float_as_uint(f);
  u += 0x7fffu + ((u >> 16) & 1u);
  return (unsigned short)(u >> 16);
}
__device__ __forceinline__ float bf2f(unsigned short h) {
  return __uint_as_float(((unsigned)h) << 16);
}
__device__ __forceinline__ float sigm(float v) { return 1.f / (1.f + __expf(-v)); }
__device__ __forceinline__ float tanh_f(float v) { return 1.f - 2.f / (__expf(2.f * v) + 1.f); }

// ---------------- fp32 -> bf16 convert (vectorized) ----------------
__global__ __launch_bounds__(256) void cvt_bf16(const float* __restrict__ src,
                                                unsigned short* __restrict__ dst, int n8) {
  int i = blockIdx.x * 256 + threadIdx.x;
  if (i >= n8) return;
  const float4 a = *(const float4*)(src + (size_t)i * 8);
  const float4 b = *(const float4*)(src + (size_t)i * 8 + 4);
  i32x4 v;
  v.x = (int)(f2bf(a.x) | ((unsigned)f2bf(a.y) << 16));
  v.y = (int)(f2bf(a.z) | ((unsigned)f2bf(a.w) << 16));
  v.z = (int)(f2bf(b.x) | ((unsigned)f2bf(b.y) << 16));
  v.w = (int)(f2bf(b.z) | ((unsigned)f2bf(b.w) << 16));
  *(i32x4*)(dst + (size_t)i * 8) = v;
}

// ---------------- Phase A: x_proj[t][n][b] = sum_k W_ih[n][k]*x[t][b][k] + b_ih[n] --------
template <int XP32>
__global__ __launch_bounds__(256) void xproj_gemm(const unsigned short* __restrict__ Wb,
                                                  const unsigned short* __restrict__ Xb,
                                                  const float* __restrict__ bias,
                                                  void* __restrict__ XPv) {
  __shared__ unsigned short Wt[64 * 40];
  __shared__ unsigned short Xt[64 * 40];
  const int tid = threadIdx.x;
  const int lane = tid & 63, wid = tid >> 6;
  const int g = lane >> 4, cc = lane & 15;
  const int n0 = blockIdx.x * 64;
  const int t = blockIdx.y;
  const size_t m0 = (size_t)t * 64;
  const int srow = tid >> 2, schunk = (tid & 3) * 8;

  f32x4 acc[4] = {};
  for (int kb = 0; kb < KD; kb += 32) {
    __syncthreads();
    *(i32x4*)&Wt[srow * 40 + schunk] = *(const i32x4*)(Wb + (size_t)(n0 + srow) * KD + kb + schunk);
    *(i32x4*)&Xt[srow * 40 + schunk] = *(const i32x4*)(Xb + (m0 + srow) * KD + kb + schunk);
    __syncthreads();
    bfrag af = *(const bfrag*)&Wt[(wid * 16 + cc) * 40 + g * 8];
#pragma unroll
    for (int mt = 0; mt < 4; ++mt) {
      bfrag bf = *(const bfrag*)&Xt[(mt * 16 + cc) * 40 + g * 8];
      acc[mt] = __builtin_amdgcn_mfma_f32_16x16x32_bf16(af, bf, acc[mt], 0, 0, 0);
    }
  }
  const int nl = wid * 16 + g * 4;
  float bi[4];
#pragma unroll
  for (int r = 0; r < 4; ++r) bi[r] = bias[n0 + nl + r];
#pragma unroll
  for (int mt = 0; mt < 4; ++mt) {
#pragma unroll
    for (int r = 0; r < 4; ++r) {
      float v = acc[mt][r] + bi[r];
      size_t idx = ((size_t)t * NG + n0 + nl + r) * 64 + mt * 16 + cc;
      if (XP32) ((float*)XPv)[idx] = v;
      else ((unsigned short*)XPv)[idx] = f2bf(v);
    }
  }
}

// ---------------- Phase B: persistent recurrence, XCD-local L2 exchange ----------------
// grid = 128, workers: (bid&7) < GB -> blk = bid&7, slice = bid>>3. With round-robin
// bid%8 -> XCD, all 16 WGs of a batch-block share one XCD; their h exchange goes
// through that XCD's L2: plain stores (write-through L1->L2) + sc0 loads (bypass L1,
// hit L2). Correctness does NOT depend on placement: producers ALWAYS duplicate into
// an sc1 (agent/MALL) shadow mailbox with its own flag ordered by vmcnt(0); consumers
// fall back to it on poll timeout (sticky after 3 consecutive).
template <int XP32>
__global__ __launch_bounds__(256, 1) void lstm_rec(const unsigned short* __restrict__ Whh,
                                                   const void* __restrict__ XPv,
                                                   const float* __restrict__ bhh,
                                                   const float* __restrict__ h0,
                                                   const float* __restrict__ c0,
                                                   unsigned short* __restrict__ mbf,
                                                   unsigned short* __restrict__ mbs,
                                                   unsigned int* __restrict__ ff,
                                                   unsigned int* __restrict__ fs,
                                                   float* __restrict__ out) {
  if ((blockIdx.x & 7) >= GB) return;  // dummy WGs (XCD-mapping filler) exit

  __shared__ unsigned short hl[16 * 512];  // h block, XOR-swizzled rows (16KB)
  __shared__ float hf[16 * 33];            // h_new transpose tile (padded)
  __shared__ unsigned mode_s;

  const int tid = threadIdx.x;
  const int lane = tid & 63, wid = tid >> 6;
  const int g = lane >> 4, cc = lane & 15;
  const int blk = blockIdx.x & 7, slice = blockIdx.x >> 3;
  const int b0 = blk * 16, d0 = slice * 32;
  unsigned int* flagf = ff + blk * 64;  // 16 slice flags = one 64B line per block
  unsigned int* flags = fs + blk * 64;

  // ---- publish our slice of h0 into parity-0 (fast plain + slow sc1)
  if (tid < 128) {
    const int b = tid >> 3, dg = (tid & 7) * 4;
    const float* hsrc = h0 + (size_t)(b0 + b) * KD + d0 + dg;
    unsigned long long pk = (unsigned long long)f2bf(hsrc[0]) |
                            ((unsigned long long)f2bf(hsrc[1]) << 16) |
                            ((unsigned long long)f2bf(hsrc[2]) << 32) |
                            ((unsigned long long)f2bf(hsrc[3]) << 48);
    const size_t ei = (size_t)blk * MB_BLK_ELEMS + b * KD + d0 + dg;
    *(unsigned long long*)(mbf + ei) = pk;
    __hip_atomic_store((unsigned long long*)(mbs + ei), pk, __ATOMIC_RELAXED,
                       __HIP_MEMORY_SCOPE_AGENT);
  }
  __syncthreads();  // full vmcnt(0) drain: both mailboxes visible
  if (tid == 0) {
    flagf[slice] = 1u;
    __hip_atomic_store(&flags[slice], 1u, __ATOMIC_RELAXED, __HIP_MEMORY_SCOPE_AGENT);
  }

  // ---- preload W_hh slice into registers: 2 tiles x 16 k-steps of bf16x8
  bfrag w[2][16];
#pragma unroll
  for (int j = 0; j < 2; ++j) {
    const int tt = wid * 2 + j;
    const int r = tt * 16 + cc;  // A-operand row = lane&15
    const size_t n = (size_t)(r & 3) * KD + d0 + (r >> 2);
#pragma unroll
    for (int ks = 0; ks < 16; ++ks)
      w[j][ks] = *(const bfrag*)(Whh + n * KD + ks * 32 + g * 8);
  }
  float bh[2][4], creg[2];
#pragma unroll
  for (int j = 0; j < 2; ++j) {
    const int d = d0 + (wid * 2 + j) * 4 + g;
#pragma unroll
    for (int r = 0; r < 4; ++r) bh[j][r] = bhh[r * KD + d];
    creg[j] = c0[(b0 + cc) * KD + d];
  }

  int slowcnt = 0;  // meaningful in wave 0 only

  for (int t = 0; t < NT; ++t) {
    // prefetch x_proj (independent of h; in flight during the spin)
    float xp[2][4];
#pragma unroll
    for (int j = 0; j < 2; ++j) {
      const int d = d0 + (wid * 2 + j) * 4 + g;
#pragma unroll
      for (int r = 0; r < 4; ++r) {
        size_t idx = ((size_t)t * NG + r * KD + d) * 64 + b0 + cc;
        xp[j][r] = XP32 ? ((const float*)XPv)[idx] : bf2f(((const unsigned short*)XPv)[idx]);
      }
    }
    // ---- wait for all 16 slices' h_t: fast sc0 poll on L2 flags, sc1 fallback.
    // flag[s] provably in {t+1, t+2} once published -> accept (f - tgt) <= 1.
    const unsigned tgt = (unsigned)(t + 1);
    if (wid == 0) {
      bool done = false;
      if (slowcnt < 3) {
        for (int it = 0; it < 32 && !done; ++it) {
          unsigned f = tgt;
          if (lane < 16) {
            const unsigned int* fp = flagf + lane;
            asm volatile("global_load_dword %0, %1, off sc0\n\ts_waitcnt vmcnt(0)"
                         : "=&v"(f) : "v"(fp) : "memory");
          }
          done = __all((f - tgt) <= 1u);
        }
      }
      unsigned mode = 0;
      if (!done) {
        ++slowcnt;
        mode = 1;
        for (;;) {
          unsigned f = tgt;
          if (lane < 16)
            f = __hip_atomic_load(flags + lane, __ATOMIC_RELAXED, __HIP_MEMORY_SCOPE_AGENT);
          if (__all((f - tgt) <= 1u)) break;
        }
      } else {
        slowcnt = 0;
      }
      if (tid == 0) mode_s = mode;
    }
    __syncthreads();
    const unsigned mode = mode_s;
    // ---- stage h block (16 x 512 bf16 = 16KB) into swizzled LDS
    if (mode == 0) {
      const char* pb = (const char*)(mbf + (size_t)(t & 1) * MB_PAR_ELEMS +
                                     (size_t)blk * MB_BLK_ELEMS);
      i32x4 va, vb, vc, vd;
      asm volatile(
          "global_load_dwordx4 %0, %4, off sc0\n\t"
          "global_load_dwordx4 %1, %5, off sc0\n\t"
          "global_load_dwordx4 %2, %6, off sc0\n\t"
          "global_load_dwordx4 %3, %7, off sc0\n\t"
          "s_waitcnt vmcnt(0)"
          : "=&v"(va), "=&v"(vb), "=&v"(vc), "=&v"(vd)
          : "v"(pb + tid * 16), "v"(pb + tid * 16 + 4096),
            "v"(pb + tid * 16 + 8192), "v"(pb + tid * 16 + 12288)
          : "memory");
      __builtin_amdgcn_sched_barrier(0);
      const int colb = (tid * 16) & 1023;
      const int r0 = tid >> 6;
#pragma unroll
      for (int j = 0; j < 4; ++j) {
        const int row = r0 + j * 4;
        *(i32x4*)((char*)hl + row * 1024 + (colb ^ ((row & 7) << 4))) =
            (j == 0) ? va : (j == 1) ? vb : (j == 2) ? vc : vd;
      }
    } else {
      const unsigned long long* hp =
          (const unsigned long long*)(mbs + (size_t)(t & 1) * MB_PAR_ELEMS +
                                      (size_t)blk * MB_BLK_ELEMS);
      unsigned long long hv8[8];
#pragma unroll
      for (int j = 0; j < 8; ++j)
        hv8[j] = __hip_atomic_load(hp + j * 256 + tid, __ATOMIC_RELAXED,
                                   __HIP_MEMORY_SCOPE_AGENT);
#pragma unroll
      for (int j = 0; j < 8; ++j) {
        const int row = j * 2 + (tid >> 7);
        const int colb = (tid & 127) * 8;
        *(unsigned long long*)((char*)hl + row * 1024 + (colb ^ ((row & 7) << 4))) = hv8[j];
      }
    }
    __syncthreads();
    // ---- gates = W_slice @ h^T (4 accumulators, chains of 8)
    f32x4 p00 = {0.f, 0.f, 0.f, 0.f}, p01 = {0.f, 0.f, 0.f, 0.f};
    f32x4 p10 = {0.f, 0.f, 0.f, 0.f}, p11 = {0.f, 0.f, 0.f, 0.f};
#pragma unroll
    for (int ks = 0; ks < 8; ++ks) {
      const int off = ks * 64 + g * 16;
      bfrag hb = *(const bfrag*)((const char*)hl + cc * 1024 + (off ^ ((cc & 7) << 4)));
      p00 = __builtin_amdgcn_mfma_f32_16x16x32_bf16(w[0][ks], hb, p00, 0, 0, 0);
      p10 = __builtin_amdgcn_mfma_f32_16x16x32_bf16(w[1][ks], hb, p10, 0, 0, 0);
    }
#pragma unroll
    for (int ks = 8; ks < 16; ++ks) {
      const int off = ks * 64 + g * 16;
      bfrag hb = *(const bfrag*)((const char*)hl + cc * 1024 + (off ^ ((cc & 7) << 4)));
      p01 = __builtin_amdgcn_mfma_f32_16x16x32_bf16(w[0][ks], hb, p01, 0, 0, 0);
      p11 = __builtin_amdgcn_mfma_f32_16x16x32_bf16(w[1][ks], hb, p11, 0, 0, 0);
    }
    const f32x4 acc0 = p00 + p01, acc1 = p10 + p11;
    // ---- pointwise (i,f,g,o thread-local)
    float hnv[2];
#pragma unroll
    for (int j = 0; j < 2; ++j) {
      const f32x4 a = j ? acc1 : acc0;
      float gi = a[0] + xp[j][0] + bh[j][0];
      float gf = a[1] + xp[j][1] + bh[j][1];
      float gg = a[2] + xp[j][2] + bh[j][2];
      float go = a[3] + xp[j][3] + bh[j][3];
      float cn = sigm(gf) * creg[j] + sigm(gi) * tanh_f(gg);
      creg[j] = cn;
      hnv[j] = sigm(go) * tanh_f(cn);
      if (t == NT - 1) out[CT_OFF + (size_t)(b0 + cc) * KD + d0 + (wid * 8 + j * 4 + g)] = cn;
    }
    // ---- publish h_{t+1}: pack dim-pairs via shfl; plain stores first, sc1 dups after
    {
      unsigned short* fb = mbf + (size_t)((t + 1) & 1) * MB_PAR_ELEMS + (size_t)blk * MB_BLK_ELEMS;
      unsigned short* sb = mbs + (size_t)((t + 1) & 1) * MB_PAR_ELEMS + (size_t)blk * MB_BLK_ELEMS;
      const float o0 = __shfl_xor(hnv[0], 16);
      const float o1 = __shfl_xor(hnv[1], 16);
      if (!(g & 1)) {
        const unsigned w0 = (unsigned)f2bf(hnv[0]) | ((unsigned)f2bf(o0) << 16);
        const unsigned w1 = (unsigned)f2bf(hnv[1]) | ((unsigned)f2bf(o1) << 16);
        const int e0 = cc * KD + d0 + wid * 8 + g;      // dims (d, d+1), 4B aligned
        const int e1 = e0 + 4;
        *(unsigned*)(fb + e0) = w0;
        *(unsigned*)(fb + e1) = w1;
        asm volatile("" ::: "memory");  // keep plain stores older than sc1 stores
        __hip_atomic_store((unsigned*)(sb + e0), w0, __ATOMIC_RELAXED, __HIP_MEMORY_SCOPE_AGENT);
        __hip_atomic_store((unsigned*)(sb + e1), w1, __ATOMIC_RELAXED, __HIP_MEMORY_SCOPE_AGENT);
      }
    }
    // hf for the fp32 output path (read after 2nd barrier)
    hf[cc * 33 + wid * 8 + g] = hnv[0];
    hf[cc * 33 + wid * 8 + 4 + g] = hnv[1];
    // split drain: vmcnt(2) -> the 2 plain stores (older) done; sc1 pair may fly
    asm volatile("s_waitcnt vmcnt(2) lgkmcnt(0)" ::: "memory");
    __builtin_amdgcn_sched_barrier(0);
    __builtin_amdgcn_s_barrier();
    if (tid == 0) flagf[slice] = (unsigned)(t + 2);  // fast flag (L2)
    asm volatile("s_waitcnt vmcnt(0)" ::: "memory");
    __builtin_amdgcn_sched_barrier(0);
    __builtin_amdgcn_s_barrier();
    if (tid == 0)
      __hip_atomic_store(&flags[slice], (unsigned)(t + 2), __ATOMIC_RELAXED,
                         __HIP_MEMORY_SCOPE_AGENT);
    // fp32 outputs, fully off the critical path
    if (tid < 128) {
      const int b = tid >> 3, dg = (tid & 7) * 4;
      float4 hv;
      hv.x = hf[b * 33 + dg];
      hv.y = hf[b * 33 + dg + 1];
      hv.z = hf[b * 33 + dg + 2];
      hv.w = hf[b * 33 + dg + 3];
      *(float4*)(out + (size_t)t * NB * KD + (size_t)(b0 + b) * KD + d0 + dg) = hv;
      if (t == NT - 1)
        *(float4*)(out + HT_OFF + (size_t)(b0 + b) * KD + d0 + dg) = hv;
    }
  }
}

extern "C" void kernel_launch(void* const* d_in, const int* in_sizes, int n_in,
                              void* d_out, int out_size, void* d_ws, size_t ws_size,
                              hipStream_t stream) {
  const float* x = (const float*)d_in[0];
  const float* h0 = (const float*)d_in[1];
  const float* c0 = (const float*)d_in[2];
  const float* Wih = (const float*)d_in[3];
  const float* Whh = (const float*)d_in[4];
  const float* bih = (const float*)d_in[5];
  const float* bhh = (const float*)d_in[6];
  float* out = (float*)d_out;
  char* ws = (char*)d_ws;

  unsigned int* ff = (unsigned int*)ws;                       // fast flags (1KB used)
  unsigned int* fs = (unsigned int*)(ws + 4096);              // slow flags
  unsigned short* mbf = (unsigned short*)(ws + 8192);         // fast mailbox 128KB
  unsigned short* mbs = (unsigned short*)(ws + 8192 + 131072);// slow mailbox 128KB
  unsigned short* WhhB = (unsigned short*)(ws + 270336);      // 2MB
  unsigned short* WihB = (unsigned short*)(ws + 270336 + 2097152);
  unsigned short* XB = (unsigned short*)(ws + 270336 + 2 * 2097152);  // 32MB
  const size_t xp_off = 270336 + 2ull * 2097152 + 33554432;
  void* XP = (void*)(ws + xp_off);
  const bool xp32 = ws_size >= xp_off + (size_t)NT * NG * 64 * 4;

  hipMemsetAsync(ws, 0, 8192, stream);  // zero both flag arrays

  const int nx8 = NT * NB * KD / 8;
  const int nw8 = NG * KD / 8;
  cvt_bf16<<<dim3(nx8 / 256), 256, 0, stream>>>(x, XB, nx8);
  cvt_bf16<<<dim3(nw8 / 256), 256, 0, stream>>>(Wih, WihB, nw8);
  cvt_bf16<<<dim3(nw8 / 256), 256, 0, stream>>>(Whh, WhhB, nw8);

  if (xp32) {
    xproj_gemm<1><<<dim3(NG / 64, NT), 256, 0, stream>>>(WihB, XB, bih, XP);
    lstm_rec<1><<<dim3(GB * GH * 2), 256, 0, stream>>>(WhhB, XP, bhh, h0, c0, mbf, mbs, ff, fs, out);
  } else {
    xproj_gemm<0><<<dim3(NG / 64, NT), 256, 0, stream>>>(WihB, XB, bih, XP);
    lstm_rec<0><<<dim3(GB * GH * 2), 256, 0, stream>>>(WhhB, XP, bhh, h0, c0, mbf, mbs, ff, fs, out);
  }
}

// Round 5
// 1911.942 us; speedup vs baseline: 1.1317x; 1.1317x over previous
//
#include <hip/hip_runtime.h>

typedef __attribute__((ext_vector_type(8))) short bfrag;   // 8 bf16 (4 VGPRs)
typedef __attribute__((ext_vector_type(4))) float f32x4;   // MFMA C/D
typedef __attribute__((ext_vector_type(4))) int i32x4;     // 16B moves

#define NT 512      // seq len
#define NB 64       // batch
#define KD 512      // D == H == 512
#define NG 2048     // 4*H gate rows
#define GB 4        // batch blocks (16 batch each)
#define NWG 256     // launched WGs for lstm_rec (registration pool)

#define YS_SZ (NT * NB * KD)
#define HT_OFF YS_SZ
#define CT_OFF (YS_SZ + NB * KD)

#define MB_BLK_ELEMS 8192             // 16 batch x 512 dims bf16 per block
#define MB_PAR_ELEMS (GB * MB_BLK_ELEMS)

__device__ __forceinline__ unsigned short f2bf(float f) {
  unsigned u = __float_as_uint(f);
  u += 0x7fffu + ((u >> 16) & 1u);
  return (unsigned short)(u >> 16);
}
__device__ __forceinline__ float bf2f(unsigned short h) {
  return __uint_as_float(((unsigned)h) << 16);
}
__device__ __forceinline__ float sigm(float v) { return 1.f / (1.f + __expf(-v)); }
__device__ __forceinline__ float tanh_f(float v) { return 1.f - 2.f / (__expf(2.f * v) + 1.f); }

// sc0 load: bypass L1, read the XCD's L2 (fresh copy of write-through stores)
__device__ __forceinline__ unsigned ld_sc0(const unsigned int* p) {
  unsigned r;
  asm volatile("global_load_dword %0, %1, off sc0\n\ts_waitcnt vmcnt(0)"
               : "=&v"(r) : "v"(p) : "memory");
  return r;
}

// ---------------- fp32 -> bf16 convert (vectorized) ----------------
__global__ __launch_bounds__(256) void cvt_bf16(const float* __restrict__ src,
                                                unsigned short* __restrict__ dst, int n8) {
  int i = blockIdx.x * 256 + threadIdx.x;
  if (i >= n8) return;
  const float4 a = *(const float4*)(src + (size_t)i * 8);
  const float4 b = *(const float4*)(src + (size_t)i * 8 + 4);
  i32x4 v;
  v.x = (int)(f2bf(a.x) | ((unsigned)f2bf(a.y) << 16));
  v.y = (int)(f2bf(a.z) | ((unsigned)f2bf(a.w) << 16));
  v.z = (int)(f2bf(b.x) | ((unsigned)f2bf(b.y) << 16));
  v.w = (int)(f2bf(b.z) | ((unsigned)f2bf(b.w) << 16));
  *(i32x4*)(dst + (size_t)i * 8) = v;
}

// ---------------- Phase A: x_proj ----------------
template <int XP32>
__global__ __launch_bounds__(256) void xproj_gemm(const unsigned short* __restrict__ Wb,
                                                  const unsigned short* __restrict__ Xb,
                                                  const float* __restrict__ bias,
                                                  void* __restrict__ XPv) {
  __shared__ unsigned short Wt[64 * 40];
  __shared__ unsigned short Xt[64 * 40];
  const int tid = threadIdx.x;
  const int lane = tid & 63, wid = tid >> 6;
  const int g = lane >> 4, cc = lane & 15;
  const int n0 = blockIdx.x * 64;
  const int t = blockIdx.y;
  const size_t m0 = (size_t)t * 64;
  const int srow = tid >> 2, schunk = (tid & 3) * 8;

  f32x4 acc[4] = {};
  for (int kb = 0; kb < KD; kb += 32) {
    __syncthreads();
    *(i32x4*)&Wt[srow * 40 + schunk] = *(const i32x4*)(Wb + (size_t)(n0 + srow) * KD + kb + schunk);
    *(i32x4*)&Xt[srow * 40 + schunk] = *(const i32x4*)(Xb + (m0 + srow) * KD + kb + schunk);
    __syncthreads();
    bfrag af = *(const bfrag*)&Wt[(wid * 16 + cc) * 40 + g * 8];
#pragma unroll
    for (int mt = 0; mt < 4; ++mt) {
      bfrag bf = *(const bfrag*)&Xt[(mt * 16 + cc) * 40 + g * 8];
      acc[mt] = __builtin_amdgcn_mfma_f32_16x16x32_bf16(af, bf, acc[mt], 0, 0, 0);
    }
  }
  const int nl = wid * 16 + g * 4;
  float bi[4];
#pragma unroll
  for (int r = 0; r < 4; ++r) bi[r] = bias[n0 + nl + r];
#pragma unroll
  for (int mt = 0; mt < 4; ++mt) {
#pragma unroll
    for (int r = 0; r < 4; ++r) {
      float v = acc[mt][r] + bi[r];
      size_t idx = ((size_t)t * NG + n0 + nl + r) * 64 + mt * 16 + cc;
      if (XP32) ((float*)XPv)[idx] = v;
      else ((unsigned short*)XPv)[idx] = f2bf(v);
    }
  }
}

// ---------------- Phase B: persistent recurrence, runtime XCD discovery ----------------
// 256 WGs register (XCC_ID via s_getreg, rank via agent atomics). First GB XCDs with
// >=16 registrants host batch-blocks; their first 16 registrants are the slices ->
// co-location by construction. Two-phase staleness handshake verifies plain-store ->
// sc0-load visibility inside each block; any failure votes the block into the proven
// agent-scope (sc1/MALL) path. ctl words: [0..7]=reg cnt, [16]=regtot, [32+blk]=vote,
// [128+blk*64 +s*4+w]=fast flags, [384+...]=slow flags, [640+...]=handshake.
template <int XP32>
__global__ __launch_bounds__(256, 1) void lstm_rec(const unsigned short* __restrict__ Whh,
                                                   const void* __restrict__ XPv,
                                                   const float* __restrict__ bhh,
                                                   const float* __restrict__ h0,
                                                   const float* __restrict__ c0,
                                                   unsigned short* __restrict__ mbf,
                                                   unsigned short* __restrict__ mbs,
                                                   unsigned int* __restrict__ ctl,
                                                   float* __restrict__ out) {
  __shared__ unsigned short hl[16 * 512];  // h block, XOR-swizzled rows (16KB)
  __shared__ float hf[16 * 33];            // h_new transpose tile (padded)
  __shared__ int sh_blk, sh_slice, sh_mode;

  const int tid = threadIdx.x;
  const int lane = tid & 63, wid = tid >> 6;
  const int g = lane >> 4, cc = lane & 15;

  // ---- registration & role assignment
  if (tid == 0) {
    unsigned xcd;
    asm volatile("s_getreg_b32 %0, hwreg(20, 0, 32)" : "=s"(xcd));  // HW_REG_XCC_ID
    xcd &= 7u;
    unsigned rank = __hip_atomic_fetch_add(&ctl[xcd], 1u, __ATOMIC_RELAXED,
                                           __HIP_MEMORY_SCOPE_AGENT);
    __hip_atomic_fetch_add(&ctl[16], 1u, __ATOMIC_RELAXED, __HIP_MEMORY_SCOPE_AGENT);
    while (__hip_atomic_load(&ctl[16], __ATOMIC_RELAXED, __HIP_MEMORY_SCOPE_AGENT) < NWG)
      __builtin_amdgcn_s_sleep(1);
    int nq = 0, myq = -1;
    for (int x2 = 0; x2 < 8; ++x2) {
      unsigned c = __hip_atomic_load(&ctl[x2], __ATOMIC_RELAXED, __HIP_MEMORY_SCOPE_AGENT);
      if (c >= 16u) { if ((unsigned)x2 == xcd) myq = nq; ++nq; }
    }
    int bk = -1, sl = 0, md = 0;
    if (nq >= GB) {
      if (myq >= 0 && myq < GB && rank < 16u) { bk = myq; sl = (int)rank; md = 1; }
    } else if (blockIdx.x < GB * 16) {  // static fallback, slow transport
      bk = (int)(blockIdx.x >> 4); sl = (int)(blockIdx.x & 15);
    }
    sh_blk = bk; sh_slice = sl; sh_mode = md;
  }
  __syncthreads();
  const int blk = sh_blk, slice = sh_slice;
  int fast = sh_mode;
  if (blk < 0) return;  // non-worker
  const int b0 = blk * 16, d0 = slice * 32;
  unsigned int* ffb = ctl + 128 + blk * 64;
  unsigned int* fsb = ctl + 384 + blk * 64;
  const int fidx = slice * 4 + wid;

  // ---- two-phase handshake: prove plain-store -> sc0-load visibility in this block
  if (fast) {
    unsigned int* hsb = ctl + 640 + blk * 64;
    if (lane == 0) *(volatile unsigned int*)(hsb + fidx) = 1u;
    asm volatile("s_waitcnt vmcnt(0)" ::: "memory");
    bool ok = false;
    for (int it = 0; it < 1024 && !ok; ++it) ok = __all(ld_sc0(hsb + lane) >= 1u);
    if (lane == 0) *(volatile unsigned int*)(hsb + fidx) = 2u;
    asm volatile("s_waitcnt vmcnt(0)" ::: "memory");
    bool ok2 = false;
    for (int it = 0; it < 1024 && !ok2; ++it) ok2 = __all(ld_sc0(hsb + lane) >= 2u);
    ok = ok && ok2;
    if (lane == 0)
      __hip_atomic_fetch_add(&ctl[32 + blk], 0x100u + (ok ? 0u : 1u), __ATOMIC_RELAXED,
                             __HIP_MEMORY_SCOPE_AGENT);
    unsigned v;
    do {
      v = __hip_atomic_load(&ctl[32 + blk], __ATOMIC_RELAXED, __HIP_MEMORY_SCOPE_AGENT);
    } while ((v >> 8) < 64u);
    fast = ((v & 0xFFu) == 0u) ? 1 : 0;
  }

  // ---- publish h0 (parity 0, tag 1) via decided transport
  if (tid < 128) {
    const int b = tid >> 3, dg = (tid & 7) * 4;
    const float* hsrc = h0 + (size_t)(b0 + b) * KD + d0 + dg;
    unsigned long long pk = (unsigned long long)f2bf(hsrc[0]) |
                            ((unsigned long long)f2bf(hsrc[1]) << 16) |
                            ((unsigned long long)f2bf(hsrc[2]) << 32) |
                            ((unsigned long long)f2bf(hsrc[3]) << 48);
    const size_t ei = (size_t)blk * MB_BLK_ELEMS + b * KD + d0 + dg;
    if (fast) *(unsigned long long*)(mbf + ei) = pk;
    else __hip_atomic_store((unsigned long long*)(mbs + ei), pk, __ATOMIC_RELAXED,
                            __HIP_MEMORY_SCOPE_AGENT);
  }
  asm volatile("s_waitcnt vmcnt(0)" ::: "memory");
  __syncthreads();
  if (lane == 0) {
    if (fast) *(volatile unsigned int*)(ffb + fidx) = 1u;
    else __hip_atomic_store(fsb + fidx, 1u, __ATOMIC_RELAXED, __HIP_MEMORY_SCOPE_AGENT);
  }

  // ---- preload W_hh slice into registers: 2 tiles x 16 k-steps of bf16x8
  bfrag w[2][16];
#pragma unroll
  for (int j = 0; j < 2; ++j) {
    const int tt = wid * 2 + j;
    const int r = tt * 16 + cc;  // A-operand row = lane&15
    const size_t n = (size_t)(r & 3) * KD + d0 + (r >> 2);
#pragma unroll
    for (int ks = 0; ks < 16; ++ks)
      w[j][ks] = *(const bfrag*)(Whh + n * KD + ks * 32 + g * 8);
  }
  float bh[2][4], creg[2];
#pragma unroll
  for (int j = 0; j < 2; ++j) {
    const int d = d0 + (wid * 2 + j) * 4 + g;
#pragma unroll
    for (int r = 0; r < 4; ++r) bh[j][r] = bhh[r * KD + d];
    creg[j] = c0[(b0 + cc) * KD + d];
  }

  for (int t = 0; t < NT; ++t) {
    // prefetch x_proj (independent of h; completes during the poll)
    float xp[2][4];
#pragma unroll
    for (int j = 0; j < 2; ++j) {
      const int d = d0 + (wid * 2 + j) * 4 + g;
#pragma unroll
      for (int r = 0; r < 4; ++r) {
        size_t idx = ((size_t)t * NG + r * KD + d) * 64 + b0 + cc;
        xp[j][r] = XP32 ? ((const float*)XPv)[idx] : bf2f(((const unsigned short*)XPv)[idx]);
      }
    }
    // ---- poll: all waves watch all 64 (slice,wave) flags; accept {t+1, t+2}
    const unsigned tgt = (unsigned)(t + 1);
    if (fast) {
      unsigned f;
      do { f = ld_sc0(ffb + lane); } while (!__all((f - tgt) <= 1u));
    } else {
      unsigned f;
      do {
        f = __hip_atomic_load(fsb + lane, __ATOMIC_RELAXED, __HIP_MEMORY_SCOPE_AGENT);
      } while (!__all((f - tgt) <= 1u));
    }
    // ---- stage h block (16 x 512 bf16 = 16KB) into swizzled LDS
    if (fast) {
      const char* pb = (const char*)(mbf + (size_t)(t & 1) * MB_PAR_ELEMS +
                                     (size_t)blk * MB_BLK_ELEMS);
      i32x4 va, vb, vc, vd;
      asm volatile(
          "global_load_dwordx4 %0, %4, off sc0\n\t"
          "global_load_dwordx4 %1, %5, off sc0\n\t"
          "global_load_dwordx4 %2, %6, off sc0\n\t"
          "global_load_dwordx4 %3, %7, off sc0\n\t"
          "s_waitcnt vmcnt(0)"
          : "=&v"(va), "=&v"(vb), "=&v"(vc), "=&v"(vd)
          : "v"(pb + tid * 16), "v"(pb + tid * 16 + 4096),
            "v"(pb + tid * 16 + 8192), "v"(pb + tid * 16 + 12288)
          : "memory");
      __builtin_amdgcn_sched_barrier(0);
      const int colb = (tid * 16) & 1023;
      const int r0 = tid >> 6;
#pragma unroll
      for (int j = 0; j < 4; ++j) {
        const int row = r0 + j * 4;
        *(i32x4*)((char*)hl + row * 1024 + (colb ^ ((row & 7) << 4))) =
            (j == 0) ? va : (j == 1) ? vb : (j == 2) ? vc : vd;
      }
    } else {
      const unsigned long long* hp =
          (const unsigned long long*)(mbs + (size_t)(t & 1) * MB_PAR_ELEMS +
                                      (size_t)blk * MB_BLK_ELEMS);
      unsigned long long hv8[8];
#pragma unroll
      for (int j = 0; j < 8; ++j)
        hv8[j] = __hip_atomic_load(hp + j * 256 + tid, __ATOMIC_RELAXED,
                                   __HIP_MEMORY_SCOPE_AGENT);
#pragma unroll
      for (int j = 0; j < 8; ++j) {
        const int row = j * 2 + (tid >> 7);
        const int colb = (tid & 127) * 8;
        *(unsigned long long*)((char*)hl + row * 1024 + (colb ^ ((row & 7) << 4))) = hv8[j];
      }
    }
    __syncthreads();
    // ---- gates = W_slice @ h^T (4 accumulators, chains of 8)
    f32x4 p00 = {0.f, 0.f, 0.f, 0.f}, p01 = {0.f, 0.f, 0.f, 0.f};
    f32x4 p10 = {0.f, 0.f, 0.f, 0.f}, p11 = {0.f, 0.f, 0.f, 0.f};
#pragma unroll
    for (int ks = 0; ks < 8; ++ks) {
      const int off = ks * 64 + g * 16;
      bfrag hb = *(const bfrag*)((const char*)hl + cc * 1024 + (off ^ ((cc & 7) << 4)));
      p00 = __builtin_amdgcn_mfma_f32_16x16x32_bf16(w[0][ks], hb, p00, 0, 0, 0);
      p10 = __builtin_amdgcn_mfma_f32_16x16x32_bf16(w[1][ks], hb, p10, 0, 0, 0);
    }
#pragma unroll
    for (int ks = 8; ks < 16; ++ks) {
      const int off = ks * 64 + g * 16;
      bfrag hb = *(const bfrag*)((const char*)hl + cc * 1024 + (off ^ ((cc & 7) << 4)));
      p01 = __builtin_amdgcn_mfma_f32_16x16x32_bf16(w[0][ks], hb, p01, 0, 0, 0);
      p11 = __builtin_amdgcn_mfma_f32_16x16x32_bf16(w[1][ks], hb, p11, 0, 0, 0);
    }
    const f32x4 acc0 = p00 + p01, acc1 = p10 + p11;
    // ---- pointwise (i,f,g,o thread-local)
    float hnv[2];
#pragma unroll
    for (int j = 0; j < 2; ++j) {
      const f32x4 a = j ? acc1 : acc0;
      float gi = a[0] + xp[j][0] + bh[j][0];
      float gf = a[1] + xp[j][1] + bh[j][1];
      float gg = a[2] + xp[j][2] + bh[j][2];
      float go = a[3] + xp[j][3] + bh[j][3];
      float cn = sigm(gf) * creg[j] + sigm(gi) * tanh_f(gg);
      creg[j] = cn;
      hnv[j] = sigm(go) * tanh_f(cn);
      if (t == NT - 1) out[CT_OFF + (size_t)(b0 + cc) * KD + d0 + (wid * 8 + j * 4 + g)] = cn;
    }
    // ---- publish h_{t+1}: shfl-pack dim pairs, store, per-wave drain + flag (no barrier)
    {
      unsigned short* mb = (fast ? mbf : mbs) +
                           (size_t)((t + 1) & 1) * MB_PAR_ELEMS + (size_t)blk * MB_BLK_ELEMS;
      const float o0 = __shfl_xor(hnv[0], 16);
      const float o1 = __shfl_xor(hnv[1], 16);
      if (!(g & 1)) {
        const unsigned w0 = (unsigned)f2bf(hnv[0]) | ((unsigned)f2bf(o0) << 16);
        const unsigned w1 = (unsigned)f2bf(hnv[1]) | ((unsigned)f2bf(o1) << 16);
        const int e0 = cc * KD + d0 + wid * 8 + g;
        const int e1 = e0 + 4;
        if (fast) {
          *(unsigned*)(mb + e0) = w0;
          *(unsigned*)(mb + e1) = w1;
        } else {
          __hip_atomic_store((unsigned*)(mb + e0), w0, __ATOMIC_RELAXED,
                             __HIP_MEMORY_SCOPE_AGENT);
          __hip_atomic_store((unsigned*)(mb + e1), w1, __ATOMIC_RELAXED,
                             __HIP_MEMORY_SCOPE_AGENT);
        }
      }
    }
    asm volatile("s_waitcnt vmcnt(0)" ::: "memory");
    if (lane == 0) {
      const unsigned tagv = (unsigned)(t + 2);
      if (fast) *(volatile unsigned int*)(ffb + fidx) = tagv;
      else __hip_atomic_store(fsb + fidx, tagv, __ATOMIC_RELAXED, __HIP_MEMORY_SCOPE_AGENT);
    }
    // ---- fp32 outputs (off the critical path)
#pragma unroll
    for (int j = 0; j < 2; ++j) hf[cc * 33 + wid * 8 + j * 4 + g] = hnv[j];
    __syncthreads();
    if (tid < 128) {
      const int b = tid >> 3, dg = (tid & 7) * 4;
      float4 hv;
      hv.x = hf[b * 33 + dg];
      hv.y = hf[b * 33 + dg + 1];
      hv.z = hf[b * 33 + dg + 2];
      hv.w = hf[b * 33 + dg + 3];
      *(float4*)(out + (size_t)t * NB * KD + (size_t)(b0 + b) * KD + d0 + dg) = hv;
      if (t == NT - 1)
        *(float4*)(out + HT_OFF + (size_t)(b0 + b) * KD + d0 + dg) = hv;
    }
  }
}

extern "C" void kernel_launch(void* const* d_in, const int* in_sizes, int n_in,
                              void* d_out, int out_size, void* d_ws, size_t ws_size,
                              hipStream_t stream) {
  const float* x = (const float*)d_in[0];
  const float* h0 = (const float*)d_in[1];
  const float* c0 = (const float*)d_in[2];
  const float* Wih = (const float*)d_in[3];
  const float* Whh = (const float*)d_in[4];
  const float* bih = (const float*)d_in[5];
  const float* bhh = (const float*)d_in[6];
  float* out = (float*)d_out;
  char* ws = (char*)d_ws;

  unsigned int* ctl = (unsigned int*)ws;                      // 8KB control
  unsigned short* mbf = (unsigned short*)(ws + 8192);         // fast mailbox 128KB
  unsigned short* mbs = (unsigned short*)(ws + 8192 + 131072);// slow mailbox 128KB
  unsigned short* WhhB = (unsigned short*)(ws + 270336);      // 2MB
  unsigned short* WihB = (unsigned short*)(ws + 270336 + 2097152);
  unsigned short* XB = (unsigned short*)(ws + 270336 + 2 * 2097152);  // 32MB
  const size_t xp_off = 270336 + 2ull * 2097152 + 33554432;
  void* XP = (void*)(ws + xp_off);
  const bool xp32 = ws_size >= xp_off + (size_t)NT * NG * 64 * 4;

  hipMemsetAsync(ws, 0, 8192, stream);  // zero registration/flag/handshake words

  const int nx8 = NT * NB * KD / 8;
  const int nw8 = NG * KD / 8;
  cvt_bf16<<<dim3(nx8 / 256), 256, 0, stream>>>(x, XB, nx8);
  cvt_bf16<<<dim3(nw8 / 256), 256, 0, stream>>>(Wih, WihB, nw8);
  cvt_bf16<<<dim3(nw8 / 256), 256, 0, stream>>>(Whh, WhhB, nw8);

  if (xp32) {
    xproj_gemm<1><<<dim3(NG / 64, NT), 256, 0, stream>>>(WihB, XB, bih, XP);
    lstm_rec<1><<<dim3(NWG), 256, 0, stream>>>(WhhB, XP, bhh, h0, c0, mbf, mbs, ctl, out);
  } else {
    xproj_gemm<0><<<dim3(NG / 64, NT), 256, 0, stream>>>(WihB, XB, bih, XP);
    lstm_rec<0><<<dim3(NWG), 256, 0, stream>>>(WhhB, XP, bhh, h0, c0, mbf, mbs, ctl, out);
  }
}

// Round 6
// 1461.320 us; speedup vs baseline: 1.4806x; 1.3084x over previous
//
#include <hip/hip_runtime.h>

typedef __attribute__((ext_vector_type(8))) short bfrag;   // 8 bf16 (4 VGPRs)
typedef __attribute__((ext_vector_type(4))) float f32x4;   // MFMA C/D
typedef __attribute__((ext_vector_type(4))) int i32x4;     // 16B moves

#define NT 512      // seq len
#define NB 64       // batch
#define KD 512      // D == H == 512
#define NG 2048     // 4*H gate rows
#define GB 4        // batch blocks (16 batch each)
#define GH 16       // h-slices (32 dims each)

#define YS_SZ (NT * NB * KD)          // 16777216
#define HT_OFF YS_SZ
#define CT_OFF (YS_SZ + NB * KD)

// mailbox: [2 parity][GB blocks][256 pairs][16 batch] of u64 {tag32 | bf16x2}
#define MB_BLK_WORDS 4096
#define MB_PAR_WORDS (GB * MB_BLK_WORDS)
#define MB_BYTES (2 * MB_PAR_WORDS * 8)   // 262144

__device__ __forceinline__ unsigned short f2bf(float f) {
  unsigned u = __float_as_uint(f);
  u += 0x7fffu + ((u >> 16) & 1u);
  return (unsigned short)(u >> 16);
}
__device__ __forceinline__ float bf2f(unsigned short h) {
  return __uint_as_float(((unsigned)h) << 16);
}
__device__ __forceinline__ float sigm(float v) { return 1.f / (1.f + __expf(-v)); }
__device__ __forceinline__ float tanh_f(float v) { return 1.f - 2.f / (__expf(2.f * v) + 1.f); }

// ---------------- fp32 -> bf16 convert (vectorized) ----------------
__global__ __launch_bounds__(256) void cvt_bf16(const float* __restrict__ src,
                                                unsigned short* __restrict__ dst, int n8) {
  int i = blockIdx.x * 256 + threadIdx.x;
  if (i >= n8) return;
  const float4 a = *(const float4*)(src + (size_t)i * 8);
  const float4 b = *(const float4*)(src + (size_t)i * 8 + 4);
  i32x4 v;
  v.x = (int)(f2bf(a.x) | ((unsigned)f2bf(a.y) << 16));
  v.y = (int)(f2bf(a.z) | ((unsigned)f2bf(a.w) << 16));
  v.z = (int)(f2bf(b.x) | ((unsigned)f2bf(b.y) << 16));
  v.w = (int)(f2bf(b.z) | ((unsigned)f2bf(b.w) << 16));
  *(i32x4*)(dst + (size_t)i * 8) = v;
}

// ---------------- Phase A: x_proj[t][n][b] = sum_k W_ih[n][k]*x[t][b][k] + b_ih[n] --------
template <int XP32>
__global__ __launch_bounds__(256) void xproj_gemm(const unsigned short* __restrict__ Wb,
                                                  const unsigned short* __restrict__ Xb,
                                                  const float* __restrict__ bias,
                                                  void* __restrict__ XPv) {
  __shared__ unsigned short Wt[64 * 40];
  __shared__ unsigned short Xt[64 * 40];
  const int tid = threadIdx.x;
  const int lane = tid & 63, wid = tid >> 6;
  const int g = lane >> 4, cc = lane & 15;
  const int n0 = blockIdx.x * 64;
  const int t = blockIdx.y;
  const size_t m0 = (size_t)t * 64;
  const int srow = tid >> 2, schunk = (tid & 3) * 8;

  f32x4 acc[4] = {};
  for (int kb = 0; kb < KD; kb += 32) {
    __syncthreads();
    *(i32x4*)&Wt[srow * 40 + schunk] = *(const i32x4*)(Wb + (size_t)(n0 + srow) * KD + kb + schunk);
    *(i32x4*)&Xt[srow * 40 + schunk] = *(const i32x4*)(Xb + (m0 + srow) * KD + kb + schunk);
    __syncthreads();
    bfrag af = *(const bfrag*)&Wt[(wid * 16 + cc) * 40 + g * 8];
#pragma unroll
    for (int mt = 0; mt < 4; ++mt) {
      bfrag bf = *(const bfrag*)&Xt[(mt * 16 + cc) * 40 + g * 8];
      acc[mt] = __builtin_amdgcn_mfma_f32_16x16x32_bf16(af, bf, acc[mt], 0, 0, 0);
    }
  }
  const int nl = wid * 16 + g * 4;
  float bi[4];
#pragma unroll
  for (int r = 0; r < 4; ++r) bi[r] = bias[n0 + nl + r];
#pragma unroll
  for (int mt = 0; mt < 4; ++mt) {
#pragma unroll
    for (int r = 0; r < 4; ++r) {
      float v = acc[mt][r] + bi[r];
      size_t idx = ((size_t)t * NG + n0 + nl + r) * 64 + mt * 16 + cc;
      if (XP32) ((float*)XPv)[idx] = v;
      else ((unsigned short*)XPv)[idx] = f2bf(v);
    }
  }
}

// ---------------- Phase B: persistent recurrence, tagged-data mailbox (fixed poll) --------
// grid = 64: blk = bid>>4 (16 batches), slice = bid&15 (32 dims).
// Single-hop exchange: producers store (tag32|bf16x2) u64 words (relaxed agent = sc1,
// 64-bit single-copy atomic) straight from the pointwise registers — NO drains, NO
// flags, NO extra barriers. Consumers poll the data words themselves with ONE inline-asm
// batch of 16 global_load_dwordx2 sc1 + a single vmcnt(0) per round; uniform re-issue of
// all 16 on any miss (no divergence). Exact-tag accept: within a parity buffer the tag
// for step t+1 can only advance to t+3 after every WG consumed t+1 (transitive dep).
template <int XP32>
__global__ __launch_bounds__(256, 1) void lstm_rec(const unsigned short* __restrict__ Whh,
                                                   const void* __restrict__ XPv,
                                                   const float* __restrict__ bhh,
                                                   const float* __restrict__ h0,
                                                   const float* __restrict__ c0,
                                                   unsigned long long* __restrict__ mbox,
                                                   float* __restrict__ out) {
  __shared__ unsigned short hl[16 * 512];  // h block, XOR-swizzled rows (16KB)
  __shared__ float hf[16 * 33];            // h_new transpose tile (padded)

  const int tid = threadIdx.x;
  const int lane = tid & 63, wid = tid >> 6;
  const int g = lane >> 4, cc = lane & 15;
  const int blk = blockIdx.x >> 4, slice = blockIdx.x & 15;
  const int b0 = blk * 16, d0 = slice * 32;

  // ---- publish our slice of h0 (tag=1) into parity-0 mailbox, ASAP (1 word/thread)
  {
    const int lp = tid >> 4, b = tid & 15;  // local pair, batch row
    const int d = d0 + lp * 2;
    const float* hp = h0 + (size_t)(b0 + b) * KD + d;
    unsigned d32 = (unsigned)f2bf(hp[0]) | ((unsigned)f2bf(hp[1]) << 16);
    __hip_atomic_store(mbox + (size_t)blk * MB_BLK_WORDS + ((d0 >> 1) + lp) * 16 + b,
                       (1ull << 32) | (unsigned long long)d32, __ATOMIC_RELAXED,
                       __HIP_MEMORY_SCOPE_AGENT);
  }

  // ---- preload W_hh slice into registers: 2 tiles x 16 k-steps of bf16x8
  bfrag w[2][16];
#pragma unroll
  for (int j = 0; j < 2; ++j) {
    const int tt = wid * 2 + j;
    const int r = tt * 16 + cc;  // A-operand row = lane&15
    const size_t n = (size_t)(r & 3) * KD + d0 + (r >> 2);
#pragma unroll
    for (int ks = 0; ks < 16; ++ks)
      w[j][ks] = *(const bfrag*)(Whh + n * KD + ks * 32 + g * 8);
  }
  float bh[2][4], creg[2];
#pragma unroll
  for (int j = 0; j < 2; ++j) {
    const int d = d0 + (wid * 2 + j) * 4 + g;
#pragma unroll
    for (int r = 0; r < 4; ++r) bh[j][r] = bhh[r * KD + d];
    creg[j] = c0[(b0 + cc) * KD + d];
  }

  for (int t = 0; t < NT; ++t) {
    // prefetch x_proj (independent of h; drains under the first poll round)
    float xp[2][4];
#pragma unroll
    for (int j = 0; j < 2; ++j) {
      const int d = d0 + (wid * 2 + j) * 4 + g;
#pragma unroll
      for (int r = 0; r < 4; ++r) {
        size_t idx = ((size_t)t * NG + r * KD + d) * 64 + b0 + cc;
        xp[j][r] = XP32 ? ((const float*)XPv)[idx] : bf2f(((const unsigned short*)XPv)[idx]);
      }
    }
    // ---- single-hop receive: batched asm poll of 16 tagged words per thread
    const unsigned long long* mbr =
        mbox + (size_t)(t & 1) * MB_PAR_WORDS + (size_t)blk * MB_BLK_WORDS;
    const unsigned tg = (unsigned)(t + 1);
    unsigned long long q0, q1, q2, q3, q4, q5, q6, q7, q8, q9, q10, q11, q12, q13, q14, q15;
#define PISSUE(r)                                                        \
  asm volatile("global_load_dwordx2 %0, %1, %2 sc1"                      \
               : "=v"(q##r)                                              \
               : "v"((unsigned)(tid * 8 + r * 2048)), "s"(mbr));
    for (;;) {
      PISSUE(0) PISSUE(1) PISSUE(2) PISSUE(3) PISSUE(4) PISSUE(5) PISSUE(6) PISSUE(7)
      PISSUE(8) PISSUE(9) PISSUE(10) PISSUE(11) PISSUE(12) PISSUE(13) PISSUE(14) PISSUE(15)
      asm volatile("s_waitcnt vmcnt(0)" ::: "memory");
      __builtin_amdgcn_sched_barrier(0);
      unsigned ok = 1u;
#define PCHK(r) ok &= ((unsigned)(q##r >> 32) == tg) ? 1u : 0u;
      PCHK(0) PCHK(1) PCHK(2) PCHK(3) PCHK(4) PCHK(5) PCHK(6) PCHK(7)
      PCHK(8) PCHK(9) PCHK(10) PCHK(11) PCHK(12) PCHK(13) PCHK(14) PCHK(15)
      if (__all(ok)) break;
    }
#undef PISSUE
#undef PCHK
    // unpack into swizzled LDS: word (r*256+tid) = pair p = r*16+(tid>>4), batch b = tid&15
    {
      const int b = tid & 15, pq = tid >> 4;
      const int bb = b * 1024, bx = (b & 7) << 4;
#define PUNP(r) \
  *(unsigned*)((char*)hl + bb + (((r * 16 + pq) * 4) ^ bx)) = (unsigned)q##r;
      PUNP(0) PUNP(1) PUNP(2) PUNP(3) PUNP(4) PUNP(5) PUNP(6) PUNP(7)
      PUNP(8) PUNP(9) PUNP(10) PUNP(11) PUNP(12) PUNP(13) PUNP(14) PUNP(15)
#undef PUNP
    }
    __syncthreads();
    // gates = W_slice @ h^T  (4 accumulators: chains of 8)
    f32x4 p00 = {0.f, 0.f, 0.f, 0.f}, p01 = {0.f, 0.f, 0.f, 0.f};
    f32x4 p10 = {0.f, 0.f, 0.f, 0.f}, p11 = {0.f, 0.f, 0.f, 0.f};
#pragma unroll
    for (int ks = 0; ks < 8; ++ks) {
      const int off = ks * 64 + g * 16;
      bfrag hb = *(const bfrag*)((const char*)hl + cc * 1024 + (off ^ ((cc & 7) << 4)));
      p00 = __builtin_amdgcn_mfma_f32_16x16x32_bf16(w[0][ks], hb, p00, 0, 0, 0);
      p10 = __builtin_amdgcn_mfma_f32_16x16x32_bf16(w[1][ks], hb, p10, 0, 0, 0);
    }
#pragma unroll
    for (int ks = 8; ks < 16; ++ks) {
      const int off = ks * 64 + g * 16;
      bfrag hb = *(const bfrag*)((const char*)hl + cc * 1024 + (off ^ ((cc & 7) << 4)));
      p01 = __builtin_amdgcn_mfma_f32_16x16x32_bf16(w[0][ks], hb, p01, 0, 0, 0);
      p11 = __builtin_amdgcn_mfma_f32_16x16x32_bf16(w[1][ks], hb, p11, 0, 0, 0);
    }
    const f32x4 acc0 = p00 + p01, acc1 = p10 + p11;
    // pointwise (i,f,g,o thread-local)
    float hnv[2];
#pragma unroll
    for (int j = 0; j < 2; ++j) {
      const f32x4 a = j ? acc1 : acc0;
      float gi = a[0] + xp[j][0] + bh[j][0];
      float gf = a[1] + xp[j][1] + bh[j][1];
      float gg = a[2] + xp[j][2] + bh[j][2];
      float go = a[3] + xp[j][3] + bh[j][3];
      float cn = sigm(gf) * creg[j] + sigm(gi) * tanh_f(gg);
      creg[j] = cn;
      hnv[j] = sigm(go) * tanh_f(cn);
      if (t == NT - 1) out[CT_OFF + (size_t)(b0 + cc) * KD + d0 + (wid * 8 + j * 4 + g)] = cn;
    }
    // ---- single-hop publish: pair dims via shfl, store (tag|bf16x2) words NOW; no drain
    {
      unsigned long long* mbw =
          mbox + (size_t)((t + 1) & 1) * MB_PAR_WORDS + (size_t)blk * MB_BLK_WORDS;
      const unsigned long long tagn = (unsigned long long)(unsigned)(t + 2) << 32;
      const float o0 = __shfl_xor(hnv[0], 16);
      const float o1 = __shfl_xor(hnv[1], 16);
      if (!(g & 1)) {
        const unsigned w0 = (unsigned)f2bf(hnv[0]) | ((unsigned)f2bf(o0) << 16);
        const unsigned w1 = (unsigned)f2bf(hnv[1]) | ((unsigned)f2bf(o1) << 16);
        const int p0 = (d0 >> 1) + wid * 4 + (g >> 1);
        const int p1 = p0 + 2;
        __hip_atomic_store(mbw + p0 * 16 + cc, tagn | (unsigned long long)w0,
                           __ATOMIC_RELAXED, __HIP_MEMORY_SCOPE_AGENT);
        __hip_atomic_store(mbw + p1 * 16 + cc, tagn | (unsigned long long)w1,
                           __ATOMIC_RELAXED, __HIP_MEMORY_SCOPE_AGENT);
      }
    }
    // transpose h_new for coalesced fp32 output stores (off critical path)
#pragma unroll
    for (int j = 0; j < 2; ++j) hf[cc * 33 + (wid * 8 + j * 4 + g)] = hnv[j];
    __syncthreads();
    if (tid < 128) {
      const int b = tid >> 3, dg = (tid & 7) * 4;
      float4 hv;
      hv.x = hf[b * 33 + dg];
      hv.y = hf[b * 33 + dg + 1];
      hv.z = hf[b * 33 + dg + 2];
      hv.w = hf[b * 33 + dg + 3];
      *(float4*)(out + (size_t)t * NB * KD + (size_t)(b0 + b) * KD + d0 + dg) = hv;
      if (t == NT - 1)
        *(float4*)(out + HT_OFF + (size_t)(b0 + b) * KD + d0 + dg) = hv;
    }
  }
}

extern "C" void kernel_launch(void* const* d_in, const int* in_sizes, int n_in,
                              void* d_out, int out_size, void* d_ws, size_t ws_size,
                              hipStream_t stream) {
  const float* x = (const float*)d_in[0];
  const float* h0 = (const float*)d_in[1];
  const float* c0 = (const float*)d_in[2];
  const float* Wih = (const float*)d_in[3];
  const float* Whh = (const float*)d_in[4];
  const float* bih = (const float*)d_in[5];
  const float* bhh = (const float*)d_in[6];
  float* out = (float*)d_out;
  char* ws = (char*)d_ws;

  unsigned long long* mbox = (unsigned long long*)ws;                      // 256KB
  unsigned short* WhhB = (unsigned short*)(ws + MB_BYTES);                 // 2MB
  unsigned short* WihB = (unsigned short*)(ws + MB_BYTES + 2097152);       // 2MB
  unsigned short* XB = (unsigned short*)(ws + MB_BYTES + 2 * 2097152);     // 32MB
  const size_t xp_off = MB_BYTES + 2ull * 2097152 + 33554432;
  void* XP = (void*)(ws + xp_off);
  const bool xp32 = ws_size >= xp_off + (size_t)NT * NG * 64 * 4;

  hipMemsetAsync(ws, 0, MB_BYTES, stream);  // reset mailbox tags (poison/replay safe)

  const int nx8 = NT * NB * KD / 8;
  const int nw8 = NG * KD / 8;
  cvt_bf16<<<dim3(nx8 / 256), 256, 0, stream>>>(x, XB, nx8);
  cvt_bf16<<<dim3(nw8 / 256), 256, 0, stream>>>(Wih, WihB, nw8);
  cvt_bf16<<<dim3(nw8 / 256), 256, 0, stream>>>(Whh, WhhB, nw8);

  if (xp32) {
    xproj_gemm<1><<<dim3(NG / 64, NT), 256, 0, stream>>>(WihB, XB, bih, XP);
    lstm_rec<1><<<dim3(GB * GH), 256, 0, stream>>>(WhhB, XP, bhh, h0, c0, mbox, out);
  } else {
    xproj_gemm<0><<<dim3(NG / 64, NT), 256, 0, stream>>>(WihB, XB, bih, XP);
    lstm_rec<0><<<dim3(GB * GH), 256, 0, stream>>>(WhhB, XP, bhh, h0, c0, mbox, out);
  }
}